// Round 10
// baseline (19012.590 us; speedup 1.0000x reference)
//
#include <hip/hip_runtime.h>
#include <hip/hip_bf16.h>
#include <cstdint>
#include <cstddef>

#define SEQ 4096
#define HID 1024
#define G4  4096
#define NWG 64       // 64 WGs x 256 threads; each WG owns 16 units (4/wave)
#define TPB 256
#define UPL 64

typedef float f32x4 __attribute__((ext_vector_type(4)));

// ---------------- persistent device scratch ------------------------------------
__device__ float g_xg  [(size_t)SEQ * G4];   // 64 MB: input preactivations
__device__ float g_y   [(size_t)SEQ * HID];  // 16 MB: bottom LSTM outputs
__device__ float g_hs  [(size_t)SEQ * HID];  // 16 MB: h per step (NaN-sentinel)
__device__ float g_upxs[(size_t)UPL * HID];  // sampled y rows (NaN-sentinel)
__device__ float g_h2s [(size_t)UPL * HID];  // top LSTM h per step (NaN-sentinel)
__device__ float g_bias2[HID];
__device__ float g_e[SEQ];
__device__ float g_p[SEQ];
__device__ float g_invden[SEQ];
__device__ float g_csum[64 * HID];

// NaN-fill all sentinel buffers each launch (end-of-kernel L2 writeback makes
// this IC-visible before k_lstm starts; no cross-call state relied upon).
__global__ __launch_bounds__(256) void k_init()
{
  const size_t i = (size_t)blockIdx.x * 256 + threadIdx.x;   // 1M threads
  const unsigned Q = 0x7fc00000u;
  const uint4 nan4 = {Q, Q, Q, Q};
  ((uint4*)g_hs)[i] = nan4;                                  // exactly 16 MB
  if (i < (size_t)UPL * HID / 4) {
    ((uint4*)g_upxs)[i] = nan4;
    ((uint4*)g_h2s)[i]  = nan4;
  }
}

// -------- coherent 16B ops straight to the coherence point (bypass L1+L2) ------
__device__ __forceinline__ void sc_store4(float* p, f32x4 v) {
  asm volatile("global_store_dwordx4 %0, %1, off sc0 sc1" :: "v"(p), "v"(v) : "memory");
}
__device__ __forceinline__ f32x4 sc_load4(const float* p) {
  f32x4 v;
  asm volatile("global_load_dwordx4 %0, %1, off sc0 sc1\n\t"
               "s_waitcnt vmcnt(0)" : "=&v"(v) : "v"(p));
  return v;
}
__device__ __forceinline__ int nan4(f32x4 c) {
  return (c.x != c.x) | (c.y != c.y) | (c.z != c.z) | (c.w != c.w);
}

// wave-0-delegated row staging: poll 1024 floats (NaN-sentinel) into LDS.
// lane l owns float4 chunks {l, 64+l, 128+l, 192+l} (coalesced 1KB/instr).
template<int SL>
__device__ __forceinline__ void stage_row(const float* __restrict__ src,
                                          float* __restrict__ dst, int l)
{
  if (SL > 0) __builtin_amdgcn_s_sleep(SL);
  const float* p0 = src + (l << 2);
  const float* p1 = p0 + 256;
  const float* p2 = p0 + 512;
  const float* p3 = p0 + 768;
  f32x4 c0, c1, c2, c3;
  asm volatile("global_load_dwordx4 %0, %4, off sc0 sc1\n\t"
               "global_load_dwordx4 %1, %5, off sc0 sc1\n\t"
               "global_load_dwordx4 %2, %6, off sc0 sc1\n\t"
               "global_load_dwordx4 %3, %7, off sc0 sc1\n\t"
               "s_waitcnt vmcnt(0)"
               : "=&v"(c0), "=&v"(c1), "=&v"(c2), "=&v"(c3)
               : "v"(p0), "v"(p1), "v"(p2), "v"(p3));
  int b0 = nan4(c0), b1 = nan4(c1), b2 = nan4(c2), b3 = nan4(c3);
  while (__any(b0 | b1 | b2 | b3)) {
    __builtin_amdgcn_s_sleep(2);
    if (b0) { c0 = sc_load4(p0); b0 = nan4(c0); }
    if (b1) { c1 = sc_load4(p1); b1 = nan4(c1); }
    if (b2) { c2 = sc_load4(p2); b2 = nan4(c2); }
    if (b3) { c3 = sc_load4(p3); b3 = nan4(c3); }
  }
  *(f32x4*)&dst[(l << 2)]       = c0;
  *(f32x4*)&dst[256 + (l << 2)] = c1;
  *(f32x4*)&dst[512 + (l << 2)] = c2;
  *(f32x4*)&dst[768 + (l << 2)] = c3;
}

// ---------------- K1: xg = x @ bot_Wih^T + (bih + bhh), fp32 tiled GEMM --------
#define BMT 128
#define BNT 128
#define BKT 32

__global__ __launch_bounds__(256) void k_gemm_xg(const float* __restrict__ A,
                                                 const float* __restrict__ B,
                                                 const float* __restrict__ bias0,
                                                 const float* __restrict__ bias1)
{
  __shared__ float As[BKT][BMT + 4];
  __shared__ float Bs[BKT][BNT + 4];
  const int t  = threadIdx.x;
  const int bn = blockIdx.x;
  const int bm = blockIdx.y;
  const int m0 = (t & 15) * 8;
  const int n0 = (t >> 4) * 8;

  float acc[8][8];
#pragma unroll
  for (int i = 0; i < 8; i++)
#pragma unroll
    for (int j = 0; j < 8; j++) acc[i][j] = 0.f;

  for (int k0 = 0; k0 < 1024; k0 += BKT) {
#pragma unroll
    for (int i = 0; i < 4; i++) {
      const int idx = i * 256 + t;
      const int m   = idx >> 3;
      const int k4  = (idx & 7) << 2;
      const float4 av = *(const float4*)&A[(size_t)(bm * BMT + m) * 1024 + k0 + k4];
      As[k4 + 0][m] = av.x; As[k4 + 1][m] = av.y; As[k4 + 2][m] = av.z; As[k4 + 3][m] = av.w;
      const float4 bv = *(const float4*)&B[(size_t)(bn * BNT + m) * 1024 + k0 + k4];
      Bs[k4 + 0][m] = bv.x; Bs[k4 + 1][m] = bv.y; Bs[k4 + 2][m] = bv.z; Bs[k4 + 3][m] = bv.w;
    }
    __syncthreads();
#pragma unroll
    for (int k = 0; k < BKT; k++) {
      float a[8], b[8];
      *(float4*)&a[0] = *(const float4*)&As[k][m0];
      *(float4*)&a[4] = *(const float4*)&As[k][m0 + 4];
      *(float4*)&b[0] = *(const float4*)&Bs[k][n0];
      *(float4*)&b[4] = *(const float4*)&Bs[k][n0 + 4];
#pragma unroll
      for (int i = 0; i < 8; i++)
#pragma unroll
        for (int j = 0; j < 8; j++) acc[i][j] = fmaf(a[i], b[j], acc[i][j]);
    }
    __syncthreads();
  }

  float bb[8];
#pragma unroll
  for (int j = 0; j < 8; j++) {
    const int gc = bn * BNT + n0 + j;
    bb[j] = bias0[gc] + bias1[gc];
  }
#pragma unroll
  for (int i = 0; i < 8; i++) {
    const size_t off = (size_t)(bm * BMT + m0 + i) * G4 + bn * BNT + n0;
    float4 v0, v1;
    v0.x = acc[i][0] + bb[0]; v0.y = acc[i][1] + bb[1]; v0.z = acc[i][2] + bb[2]; v0.w = acc[i][3] + bb[3];
    v1.x = acc[i][4] + bb[4]; v1.y = acc[i][5] + bb[5]; v1.z = acc[i][6] + bb[6]; v1.w = acc[i][7] + bb[7];
    *(float4*)&g_xg[off]     = v0;
    *(float4*)&g_xg[off + 4] = v1;
  }
}

// ---------------- K2: persistent LSTM, 4-units/wave + NaN-sentinel dataflow ----
// Wave q of WG w owns units u0..u0+3, u0 = w*16 + q*4. Lane l: gate g = l>>4,
// col segment j = l&15 (64 cols = 16 f32x4 chunks, rotated for bank spread).
// Per lane: 4 rows x 64 cols = 64 f32x4 weights in VGPRs, reused across units.

__device__ __forceinline__ void load_weights(f32x4 wv[4][16], const float* __restrict__ W,
                                             int g, int u0, int j)
{
#pragma unroll
  for (int u = 0; u < 4; u++) {
    const float* r = W + (size_t)((g << 10) + u0 + u) * HID;
#pragma unroll
    for (int k = 0; k < 16; k++) {
      const int c = (j << 4) + ((k + j) & 15);
      wv[u][k] = *(const f32x4*)&r[c << 2];
    }
  }
}

__device__ __forceinline__ f32x4 dot_reduce(const f32x4 wv[4][16],
                                            const float* __restrict__ hb, int j)
{
  f32x4 a0 = {0.f,0.f,0.f,0.f}, a1 = {0.f,0.f,0.f,0.f};
  f32x4 a2 = {0.f,0.f,0.f,0.f}, a3 = {0.f,0.f,0.f,0.f};
#pragma unroll
  for (int k = 0; k < 16; k++) {
    const int c = (j << 4) + ((k + j) & 15);
    const f32x4 hv = *(const f32x4*)&hb[c << 2];
    a0 += wv[0][k] * hv;
    a1 += wv[1][k] * hv;
    a2 += wv[2][k] * hv;
    a3 += wv[3][k] * hv;
  }
  f32x4 r;
  r.x = (a0.x + a0.y) + (a0.z + a0.w);
  r.y = (a1.x + a1.y) + (a1.z + a1.w);
  r.z = (a2.x + a2.y) + (a2.z + a2.w);
  r.w = (a3.x + a3.y) + (a3.z + a3.w);
#pragma unroll
  for (int m = 1; m < 16; m <<= 1) {
    r.x += __shfl_xor(r.x, m);
    r.y += __shfl_xor(r.y, m);
    r.z += __shfl_xor(r.z, m);
    r.w += __shfl_xor(r.w, m);
  }
  return r;   // gate g's preactivation for the wave's 4 units (uniform in group)
}

__device__ __forceinline__ f32x4 shfl4(f32x4 v, int src) {
  f32x4 r;
  r.x = __shfl(v.x, src); r.y = __shfl(v.y, src);
  r.z = __shfl(v.z, src); r.w = __shfl(v.w, src);
  return r;
}
__device__ __forceinline__ f32x4 sig4(f32x4 x) {
  f32x4 r;
  r.x = 1.f / (1.f + expf(-x.x)); r.y = 1.f / (1.f + expf(-x.y));
  r.z = 1.f / (1.f + expf(-x.z)); r.w = 1.f / (1.f + expf(-x.w));
  return r;
}
__device__ __forceinline__ f32x4 tanh4(f32x4 x) {
  f32x4 r;
  r.x = tanhf(x.x); r.y = tanhf(x.y); r.z = tanhf(x.z); r.w = tanhf(x.w);
  return r;
}

__global__ __launch_bounds__(TPB, 1) void k_lstm(
    const float* __restrict__ bot_Whh,
    const float* __restrict__ top_Wih, const float* __restrict__ top_Whh,
    const float* __restrict__ top_bih, const float* __restrict__ top_bhh,
    const float* __restrict__ hw_b,    const float* __restrict__ cw_w,
    const float* __restrict__ cw_b,    const float* __restrict__ att_bias)
{
  const int w  = blockIdx.x;            // 0..63
  const int t  = threadIdx.x;           // 0..255
  const int q  = t >> 6;                // wave 0..3
  const int l  = t & 63;
  const int g  = l >> 4;                // gate 0..3
  const int j  = l & 15;                // col segment 0..15
  const int u0 = (w << 4) + (q << 2);   // first of 4 owned units
  const int gofs = (g << 10) + u0;      // gate*1024 + u0

  __shared__ float hbuf[2][HID];        // parity-double-buffered h stage
  __shared__ f32x4 xg2[UPL][4][4];      // [s][gate][wave] (4 units each)

  f32x4 wv[4][16];
  load_weights(wv, bot_Whh, g, u0, j);

  f32x4 c4 = {0.f,0.f,0.f,0.f};
  f32x4 xv = *(const f32x4*)&g_xg[gofs];   // step 0 xval

  // ---- bottom LSTM: 4096 sequential steps, ONE barrier per step ----
  for (int step = 0; step < SEQ; step++) {
    if (q == 0) {
      if (step == 0) {
#pragma unroll
        for (int k = 0; k < 4; k++) {
          const f32x4 z = {0.f,0.f,0.f,0.f};
          *(f32x4*)&hbuf[0][k * 256 + (l << 2)] = z;
        }
      } else {
        stage_row<12>(&g_hs[(size_t)(step - 1) << 10], hbuf[step & 1], l);
      }
    }
    __syncthreads();

    // prefetch next step's xval (hidden under the dot)
    const int ns = (step + 1 < SEQ) ? step + 1 : SEQ - 1;
    const f32x4 xvn = *(const f32x4*)&g_xg[((size_t)ns << 12) + gofs];

    f32x4 r = dot_reduce(wv, hbuf[step & 1], j);
    r += xv;

    const f32x4 gi = shfl4(r, 0);
    const f32x4 gf = shfl4(r, 16);
    const f32x4 gg = shfl4(r, 32);
    const f32x4 go = shfl4(r, 48);
    c4 = sig4(gf) * c4 + sig4(gi) * tanh4(gg);
    const f32x4 h4 = sig4(go) * tanh4(c4);

    if (l == 0) {
      sc_store4(&g_hs[((size_t)step << 10) + u0], h4);      // coherent publish
      *(f32x4*)&g_y[((size_t)step << 10) + u0] = h4;        // plain, for later kernels
      if ((step & 63) == 63)
        sc_store4(&g_upxs[((size_t)(step >> 6) << 10) + u0], h4);
    }
    xv = xvn;
  }

  // ---- top-LSTM input projection: xg2[s] = upx[s] @ top_Wih^T + bias ----
  load_weights(wv, top_Wih, g, u0, j);
  const f32x4 tb = *(const f32x4*)&top_bih[gofs] + *(const f32x4*)&top_bhh[gofs];
  for (int s = 0; s < UPL; s++) {
    if (q == 0) stage_row<0>(&g_upxs[(size_t)s << 10], hbuf[s & 1], l);
    __syncthreads();
    f32x4 r = dot_reduce(wv, hbuf[s & 1], j);
    if (j == 0) xg2[s][g][q] = r + tb;
  }

  // ---- top recurrence: 64 steps ----
  load_weights(wv, top_Whh, g, u0, j);
  c4.x = 0.f; c4.y = 0.f; c4.z = 0.f; c4.w = 0.f;
  for (int s = 0; s < UPL; s++) {
    if (q == 0) {
      if (s == 0) {
#pragma unroll
        for (int k = 0; k < 4; k++) {
          const f32x4 z = {0.f,0.f,0.f,0.f};
          *(f32x4*)&hbuf[0][k * 256 + (l << 2)] = z;
        }
      } else {
        stage_row<4>(&g_h2s[(size_t)(s - 1) << 10], hbuf[s & 1], l);
      }
    }
    __syncthreads();
    f32x4 r = dot_reduce(wv, hbuf[s & 1], j);
    r += xg2[s][g][q];
    const f32x4 gi = shfl4(r, 0);
    const f32x4 gf = shfl4(r, 16);
    const f32x4 gg = shfl4(r, 32);
    const f32x4 go = shfl4(r, 48);
    c4 = sig4(gf) * c4 + sig4(gi) * tanh4(gg);
    const f32x4 h4 = sig4(go) * tanh4(c4);
    if (l == 0)
      sc_store4(&g_h2s[((size_t)s << 10) + u0], h4);
  }

  // ---- bias2[u] = hw_b + cw_b + att_bias + ctx @ cw_w^T (ctx = h2[63]) ----
  if (q == 0) stage_row<0>(&g_h2s[(size_t)63 << 10], hbuf[0], l);
  __syncthreads();
  {
    // per wave: rows u0..u0+3; lane l handles cols [16l, 16l+16)
    f32x4 a0 = {0.f,0.f,0.f,0.f}, a1 = {0.f,0.f,0.f,0.f};
    f32x4 a2 = {0.f,0.f,0.f,0.f}, a3 = {0.f,0.f,0.f,0.f};
#pragma unroll
    for (int k = 0; k < 4; k++) {
      const f32x4 hv = *(const f32x4*)&hbuf[0][(l << 4) + (k << 2)];
      a0 += (*(const f32x4*)&cw_w[(size_t)(u0 + 0) * HID + (l << 4) + (k << 2)]) * hv;
      a1 += (*(const f32x4*)&cw_w[(size_t)(u0 + 1) * HID + (l << 4) + (k << 2)]) * hv;
      a2 += (*(const f32x4*)&cw_w[(size_t)(u0 + 2) * HID + (l << 4) + (k << 2)]) * hv;
      a3 += (*(const f32x4*)&cw_w[(size_t)(u0 + 3) * HID + (l << 4) + (k << 2)]) * hv;
    }
    f32x4 r;
    r.x = (a0.x + a0.y) + (a0.z + a0.w);
    r.y = (a1.x + a1.y) + (a1.z + a1.w);
    r.z = (a2.x + a2.y) + (a2.z + a2.w);
    r.w = (a3.x + a3.y) + (a3.z + a3.w);
#pragma unroll
    for (int m = 1; m < 64; m <<= 1) {
      r.x += __shfl_xor(r.x, m);
      r.y += __shfl_xor(r.y, m);
      r.z += __shfl_xor(r.z, m);
      r.w += __shfl_xor(r.w, m);
    }
    if (l == 0) {
      const f32x4 b = *(const f32x4*)&hw_b[u0];
      const f32x4 cb = *(const f32x4*)&cw_b[u0];
      const f32x4 ab = *(const f32x4*)&att_bias[u0];
      *(f32x4*)&g_bias2[u0] = r + b + cb + ab;
    }
  }
}

// ---------------- K3: e[t] = sum_j v2s_w[j]*tanh(y_t . hw_w[j] + bias2[j]) ----
__global__ __launch_bounds__(256) void k_attn_e(const float* __restrict__ hw_w,
                                                const float* __restrict__ v2s_w,
                                                const float* __restrict__ v2s_b)
{
  __shared__ float ys[16][1028];
  __shared__ float ws[16][1028];
  const int b  = blockIdx.x;
  const int t  = threadIdx.x;
  const int rg = t >> 6;
  const int fg = (t >> 4) & 3;
  const int ks = t & 15;

#pragma unroll
  for (int i = 0; i < 16; i++) {
    const int idx = i * 256 + t;
    const int r   = idx >> 8;
    const int c4  = (idx & 255) << 2;
    *(float4*)&ys[r][c4] = *(const float4*)&g_y[(size_t)((b << 4) + r) * HID + c4];
  }

  float e_acc[4] = {0.f, 0.f, 0.f, 0.f};
  for (int f0 = 0; f0 < HID; f0 += 16) {
    __syncthreads();
#pragma unroll
    for (int i = 0; i < 16; i++) {
      const int idx = i * 256 + t;
      const int r   = idx >> 8;
      const int c4  = (idx & 255) << 2;
      *(float4*)&ws[r][c4] = *(const float4*)&hw_w[(size_t)(f0 + r) * HID + c4];
    }
    __syncthreads();

    float acc[4][4];
#pragma unroll
    for (int u = 0; u < 4; u++)
#pragma unroll
      for (int v = 0; v < 4; v++) acc[u][v] = 0.f;

#pragma unroll
    for (int m = 0; m < 16; m++) {
      const int k4 = (ks << 6) + (((m + ks) & 15) << 2);
      float4 av[4], bv[4];
#pragma unroll
      for (int u = 0; u < 4; u++) av[u] = *(const float4*)&ys[(rg << 2) + u][k4];
#pragma unroll
      for (int v = 0; v < 4; v++) bv[v] = *(const float4*)&ws[(fg << 2) + v][k4];
#pragma unroll
      for (int u = 0; u < 4; u++)
#pragma unroll
        for (int v = 0; v < 4; v++) {
          acc[u][v] = fmaf(av[u].x, bv[v].x, acc[u][v]);
          acc[u][v] = fmaf(av[u].y, bv[v].y, acc[u][v]);
          acc[u][v] = fmaf(av[u].z, bv[v].z, acc[u][v]);
          acc[u][v] = fmaf(av[u].w, bv[v].w, acc[u][v]);
        }
    }
#pragma unroll
    for (int u = 0; u < 4; u++)
#pragma unroll
      for (int v = 0; v < 4; v++) {
        float s2 = acc[u][v];
        s2 += __shfl_xor(s2, 8);
        s2 += __shfl_xor(s2, 4);
        s2 += __shfl_xor(s2, 2);
        s2 += __shfl_xor(s2, 1);
        acc[u][v] = s2;
      }
    if (ks == 0) {
#pragma unroll
      for (int v = 0; v < 4; v++) {
        const int jj = f0 + (fg << 2) + v;
        const float bias = g_bias2[jj];
        const float vw   = v2s_w[jj];
#pragma unroll
        for (int u = 0; u < 4; u++)
          e_acc[u] += vw * tanhf(acc[u][v] + bias);
      }
    }
  }
#pragma unroll
  for (int u = 0; u < 4; u++) {
    float s2 = e_acc[u];
    s2 += __shfl_xor(s2, 16);
    s2 += __shfl_xor(s2, 32);
    if (fg == 0 && ks == 0) g_e[(b << 4) + (rg << 2) + u] = s2 + v2s_b[0];
  }
}

// ---------------- K4a: p = exp(e - max e); invden = 1/cumsum(p) --------------
__global__ __launch_bounds__(1024) void k_softmax()
{
  const int t  = threadIdx.x;
  const int ln = t & 63;
  const int wv = t >> 6;
  __shared__ float sred[16];
  __shared__ float soff[16];
  __shared__ float sM;

  const float4 ev = *(const float4*)&g_e[t << 2];
  float mx = fmaxf(fmaxf(ev.x, ev.y), fmaxf(ev.z, ev.w));
#pragma unroll
  for (int d = 32; d >= 1; d >>= 1) mx = fmaxf(mx, __shfl_xor(mx, d));
  if (ln == 0) sred[wv] = mx;
  __syncthreads();
  if (t == 0) {
    float m2 = sred[0];
    for (int i = 1; i < 16; i++) m2 = fmaxf(m2, sred[i]);
    sM = m2;
  }
  __syncthreads();
  const float M = sM;
  float4 pv;
  pv.x = expf(ev.x - M); pv.y = expf(ev.y - M); pv.z = expf(ev.z - M); pv.w = expf(ev.w - M);
  *(float4*)&g_p[t << 2] = pv;

  const float s = pv.x + pv.y + pv.z + pv.w;
  float ps = s;
#pragma unroll
  for (int d = 1; d < 64; d <<= 1) {
    const float v = __shfl_up(ps, d);
    if (ln >= d) ps += v;
  }
  __syncthreads();
  if (ln == 63) sred[wv] = ps;
  __syncthreads();
  if (t == 0) {
    float r = 0.f;
    for (int i = 0; i < 16; i++) { soff[i] = r; r += sred[i]; }
  }
  __syncthreads();
  const float base = soff[wv] + (ps - s);
  const float d0 = base + pv.x;
  const float d1 = d0 + pv.y;
  const float d2 = d1 + pv.z;
  const float d3 = d2 + pv.w;
  float4 iv;
  iv.x = 1.f / d0; iv.y = 1.f / d1; iv.z = 1.f / d2; iv.w = 1.f / d3;
  *(float4*)&g_invden[t << 2] = iv;
}

// ---------------- K4b/c/d: chunked column scan of cumsum(p*y)/den ------------
__global__ __launch_bounds__(256) void k_csum()
{
  const int ch = blockIdx.x;
  const int t  = threadIdx.x;
  float ax = 0.f, ay = 0.f, az = 0.f, aw = 0.f;
  for (int r = 0; r < 64; r++) {
    const int row = (ch << 6) + r;
    const float pr = g_p[row];
    const float4 yv = *(const float4*)&g_y[(size_t)row * HID + (t << 2)];
    ax = fmaf(pr, yv.x, ax); ay = fmaf(pr, yv.y, ay);
    az = fmaf(pr, yv.z, az); aw = fmaf(pr, yv.w, aw);
  }
  float4 o; o.x = ax; o.y = ay; o.z = az; o.w = aw;
  *(float4*)&g_csum[(ch << 10) + (t << 2)] = o;
}

__global__ __launch_bounds__(256) void k_cscan()
{
  const int c = blockIdx.x * 256 + threadIdx.x;
  float run = 0.f;
  for (int ch = 0; ch < 64; ch++) {
    const float v = g_csum[(ch << 10) + c];
    g_csum[(ch << 10) + c] = run;
    run += v;
  }
}

__global__ __launch_bounds__(256) void k_final(float* __restrict__ out)
{
  const int ch = blockIdx.x;
  const int t  = threadIdx.x;
  float4 run = *(const float4*)&g_csum[(ch << 10) + (t << 2)];
  for (int r = 0; r < 64; r++) {
    const int row = (ch << 6) + r;
    const float pr = g_p[row];
    const float iv = g_invden[row];
    const float4 yv = *(const float4*)&g_y[(size_t)row * HID + (t << 2)];
    run.x = fmaf(pr, yv.x, run.x);
    run.y = fmaf(pr, yv.y, run.y);
    run.z = fmaf(pr, yv.z, run.z);
    run.w = fmaf(pr, yv.w, run.w);
    float4 ov;
    ov.x = run.x * iv; ov.y = run.y * iv; ov.z = run.z * iv; ov.w = run.w * iv;
    *(float4*)&out[(size_t)row * HID + (t << 2)] = ov;
  }
}

// ---------------- host launch --------------------------------------------------
extern "C" void kernel_launch(void* const* d_in, const int* in_sizes, int n_in,
                              void* d_out, int out_size, void* d_ws, size_t ws_size,
                              hipStream_t stream)
{
  (void)in_sizes; (void)n_in; (void)d_ws; (void)ws_size; (void)out_size;

  const float* x        = (const float*)d_in[0];
  const float* bot_Wih  = (const float*)d_in[1];
  const float* bot_Whh  = (const float*)d_in[2];
  const float* bot_bih  = (const float*)d_in[3];
  const float* bot_bhh  = (const float*)d_in[4];
  const float* top_Wih  = (const float*)d_in[5];
  const float* top_Whh  = (const float*)d_in[6];
  const float* top_bih  = (const float*)d_in[7];
  const float* top_bhh  = (const float*)d_in[8];
  const float* hw_w     = (const float*)d_in[9];
  const float* hw_b     = (const float*)d_in[10];
  const float* cw_w     = (const float*)d_in[11];
  const float* cw_b     = (const float*)d_in[12];
  const float* att_bias = (const float*)d_in[13];
  const float* v2s_w    = (const float*)d_in[14];
  const float* v2s_b    = (const float*)d_in[15];
  float* out = (float*)d_out;

  k_init<<<dim3(4096), dim3(256), 0, stream>>>();
  k_gemm_xg<<<dim3(32, 32), dim3(256), 0, stream>>>(x, bot_Wih, bot_bih, bot_bhh);
  k_lstm<<<dim3(NWG), dim3(TPB), 0, stream>>>(bot_Whh, top_Wih, top_Whh,
                                              top_bih, top_bhh,
                                              hw_b, cw_w, cw_b, att_bias);
  k_attn_e<<<dim3(256), dim3(256), 0, stream>>>(hw_w, v2s_w, v2s_b);
  k_softmax<<<dim3(1), dim3(1024), 0, stream>>>();
  k_csum<<<dim3(64), dim3(256), 0, stream>>>();
  k_cscan<<<dim3(4), dim3(256), 0, stream>>>();
  k_final<<<dim3(64), dim3(256), 0, stream>>>(out);
}